// Round 7
// baseline (147.247 us; speedup 1.0000x reference)
//
#include <hip/hip_runtime.h>
#include <hip/hip_bf16.h>
#include <cmath>

#define B_   4
#define NT_  2048
#define G_   4096
#define DZ_  128

typedef __attribute__((ext_vector_type(8))) short bf16x8;
typedef __attribute__((ext_vector_type(4))) float f32x4;

__device__ __forceinline__ float softplus_f(float x) {
    return fmaxf(x, 0.0f) + log1pf(expf(-fabsf(x)));
}

// z_grid (B,G,DZ) fp32 -> Zt2 tiled bf16: Zt2[((b*128 + c)*128 + z)*32 + gi],
// c = g>>5, gi = g&31.  Each 8 KB chunk-tile is contiguous.  (unchanged)
__global__ __launch_bounds__(256, 1)
void transpose_z(const float* __restrict__ z, unsigned short* __restrict__ zt)
{
    __shared__ unsigned short tile[64][66];
    const int bx = blockIdx.x;                // 4b * 64gt * 2zt = 512
    const int zti = bx & 1;
    const int gt  = (bx >> 1) & 63;
    const int b   = bx >> 7;
    const int g0 = gt * 64, z0 = zti * 64;
    const int tid = threadIdx.x;
    const int zl = tid & 63, gl = tid >> 6;
    #pragma unroll
    for (int i = 0; i < 16; ++i) {
        const int g = gl + i * 4;
        const float v = z[(size_t)(b * G_ + g0 + g) * DZ_ + z0 + zl];
        unsigned int u = __float_as_uint(v);
        u = u + 0x7FFFu + ((u >> 16) & 1u);   // RNE to bf16
        tile[g][zl] = (unsigned short)(u >> 16);
    }
    __syncthreads();
    const int gp = (tid & 31) * 2, zi = tid >> 5;
    const int c  = (g0 + gp) >> 5, gi = gp & 31;
    #pragma unroll
    for (int i = 0; i < 8; ++i) {
        const int zz = zi + i * 8;
        const unsigned int lo = tile[gp][zz], hi = tile[gp + 1][zz];
        *(unsigned int*)(zt + ((size_t)(b * 128 + c) * 128 + z0 + zz) * 32 + gi)
            = lo | (hi << 16);
    }
}

// v7: 1024-thr block (16 waves, FORCED 4 waves/SIMD — the occupancy v1 had
// and every 8-wave Tt=32 variant lost).  16 waves = 2 ts x 2 k x 4 p:
//  - ts: t-set (16 rows each of the 32-row tile)
//  - k : kernel index split ACROSS waves -> acc halves to 32 AGPRs and the
//        weight transient halves, fitting the 128-reg/wave cap at 4/SIMD
//        without spill (v2's failure mode).  Only d/q math is duplicated.
//  - p : g-group (1024 g = 32 chunks of 32 g)
// The 4 (ts,k) waves of a p-group read the SAME B stream (L1/L2 hits keep
// Zt L2 traffic at 256 MB).  Register-streamed: no LDS, no barriers in the
// main loop.  Single-buffered bz (WAR resolves at MFMA issue; weights phase
// + 4-way TLP cover L2 latency); xv reloaded per chunk, issued BEFORE bz so
// its wait leaves bz in flight.
__global__ __launch_bounds__(1024, 4)
void setconv_main(const float* __restrict__ xt,
                  const float* __restrict__ xg,
                  const float* __restrict__ lsp,
                  const unsigned short* __restrict__ Zt,
                  float* __restrict__ out)
{
    __shared__ __align__(16) float red[16384];   // 64 KB, reduction only

    const int bx = blockIdx.x;                // 256 blocks = 4b x 64tt
    const int b  = bx & 3;
    const int tt = bx >> 2;                   // 0..63
    const int tid  = threadIdx.x;
    const int w    = tid >> 6;                // 0..15
    const int p    = w & 3;                   // g-group
    const int kk   = (w >> 2) & 1;            // kernel index
    const int ts   = w >> 3;                  // t-set
    const int lane = tid & 63;
    const int quad = lane >> 4;
    const int l15  = lane & 15;
    const int t0   = tt * 32;

    float c0, c1;
    {
        const float h = -0.72134752f;         // -0.5*log2(e)
        float ls;
        ls = 1e-5f + softplus_f(lsp[2 * 0 + kk]); c0 = h / (ls * ls);  // dim0, my k
        ls = 1e-5f + softplus_f(lsp[2 * 1 + kk]); c1 = h / (ls * ls);  // dim1, my k
    }

    // this wave's 16 t-rows
    const float xt0 = xt[(size_t)(b * NT_ + t0 + ts * 16 + l15) * 2 + 0];
    const float xt1 = xt[(size_t)(b * NT_ + t0 + ts * 16 + l15) * 2 + 1];

    f32x4 acc[8];                             // [nt] = 32 regs (AGPR)
    #pragma unroll
    for (int n = 0; n < 8; ++n) acc[n] = (f32x4)0.0f;

    // B-frag base: chunk c at +c*4096 shorts, frag nt at +nt*512 shorts;
    // per-lane l15*32 + quad*8 shorts (16 B/lane, fully coalesced).
    const unsigned short* zb = Zt + (size_t)(b * 128 + p * 32) * 4096
                               + l15 * 32 + quad * 8;
    const float* xgq = xg + (size_t)(b * G_ + p * 1024 + quad * 8) * 2;

    for (int ch = 0; ch < 32; ++ch) {
        // xv(ch) first (its wait leaves the newer bz loads in flight)
        const float* xp = xgq + ch * 64;
        const float4 xv0 = *(const float4*)(xp + 0);
        const float4 xv1 = *(const float4*)(xp + 4);
        const float4 xv2 = *(const float4*)(xp + 8);
        const float4 xv3 = *(const float4*)(xp + 12);
        // B(ch)
        bf16x8 bz[8];
        const unsigned short* zc = zb + (size_t)ch * 4096;
        #pragma unroll
        for (int nt = 0; nt < 8; ++nt)
            bz[nt] = *(const bf16x8*)(zc + nt * 512);
        // weights(ch) for my k only
        float gx[8], gy[8];
        gx[0]=xv0.x; gy[0]=xv0.y; gx[1]=xv0.z; gy[1]=xv0.w;
        gx[2]=xv1.x; gy[2]=xv1.y; gx[3]=xv1.z; gy[3]=xv1.w;
        gx[4]=xv2.x; gy[4]=xv2.y; gx[5]=xv2.z; gy[5]=xv2.w;
        gx[6]=xv3.x; gy[6]=xv3.y; gx[7]=xv3.z; gy[7]=xv3.w;
        union { bf16x8 v; unsigned int u[4]; } a;
        unsigned int wb[8];
        #pragma unroll
        for (int j = 0; j < 8; ++j) {
            const float d0 = xt0 - gx[j];
            const float d1 = xt1 - gy[j];
            const float e  = fmaf(d1 * d1, c1, (d0 * d0) * c0);
            wb[j] = __float_as_uint(__builtin_amdgcn_exp2f(e));
        }
        #pragma unroll
        for (int h = 0; h < 4; ++h)
            a.u[h] = __builtin_amdgcn_perm(wb[2*h+1], wb[2*h], 0x07060302u);
        // MFMA(ch)
        #pragma unroll
        for (int nt = 0; nt < 8; ++nt)
            acc[nt] = __builtin_amdgcn_mfma_f32_16x16x32_bf16(a.v, bz[nt], acc[nt], 0, 0, 0);
    }

    // ---- 2-round p-reduction per (ts,k) group (4 groups in parallel) ----
    // group base slot: (ts*2+kk)*2; slot = 2048 floats (8 KB); 8 slots = 64 KB
    const int sg = (ts * 2 + kk) * 2;
    #define RED_W(slot) { \
        float* bp = &red[(slot) * 2048 + lane * 4]; \
        _Pragma("unroll") \
        for (int n = 0; n < 8; ++n) \
            *(f32x4*)(bp + n * 256) = acc[n]; }
    #define RED_A(slot) { \
        const float* bp = &red[(slot) * 2048 + lane * 4]; \
        _Pragma("unroll") \
        for (int n = 0; n < 8; ++n) \
            acc[n] += *(const f32x4*)(bp + n * 256); }

    __syncthreads();
    if (p == 2) RED_W(sg);
    if (p == 3) RED_W(sg + 1);
    __syncthreads();
    if (p == 0) RED_A(sg);
    if (p == 1) RED_A(sg + 1);
    __syncthreads();                          // protect slot overwrite
    if (p == 1) RED_W(sg);
    __syncthreads();
    if (p == 0) {
        RED_A(sg);
        const int tr = t0 + ts * 16 + quad * 4;
        #pragma unroll
        for (int nt = 0; nt < 8; ++nt) {
            float* ob = out + (size_t)(b * NT_ + tr) * (DZ_ * 2)
                        + (nt * 16 + l15) * 2 + kk;
            #pragma unroll
            for (int r = 0; r < 4; ++r)
                ob[(size_t)r * (DZ_ * 2)] = acc[nt][r];
        }
    }
    #undef RED_W
    #undef RED_A
}

extern "C" void kernel_launch(void* const* d_in, const int* in_sizes, int n_in,
                              void* d_out, int out_size, void* d_ws, size_t ws_size,
                              hipStream_t stream)
{
    const float* x_grid = (const float*)d_in[0];   // (4,64,64,2)
    const float* z_grid = (const float*)d_in[1];   // (4,64,64,128)
    const float* xt     = (const float*)d_in[2];   // (4,2048,2)
    const float* lsp    = (const float*)d_in[3];   // (2,2)
    float* out = (float*)d_out;                    // (4,2048,256) fp32
    unsigned short* Zt = (unsigned short*)d_ws;    // tiled, 4 MB

    hipLaunchKernelGGL(transpose_z, dim3(512), dim3(256), 0, stream, z_grid, Zt);
    hipLaunchKernelGGL(setconv_main, dim3(256), dim3(1024), 0, stream,
                       xt, x_grid, lsp, Zt, out);
}

// Round 8
// 118.234 us; speedup vs baseline: 1.2454x; 1.2454x over previous
//
#include <hip/hip_runtime.h>
#include <hip/hip_bf16.h>
#include <cmath>

#define B_   4
#define NT_  2048
#define G_   4096
#define DZ_  128

typedef __attribute__((ext_vector_type(8))) short bf16x8;
typedef __attribute__((ext_vector_type(4))) float f32x4;

__device__ __forceinline__ float softplus_f(float x) {
    return fmaxf(x, 0.0f) + log1pf(expf(-fabsf(x)));
}

// z_grid (B,G,DZ) fp32 -> Zt2 tiled bf16: Zt2[((b*128 + c)*128 + z)*32 + gi],
// c = g>>5, gi = g&31.  Each 8 KB chunk-tile is contiguous.  (unchanged)
__global__ __launch_bounds__(256, 1)
void transpose_z(const float* __restrict__ z, unsigned short* __restrict__ zt)
{
    __shared__ unsigned short tile[64][66];
    const int bx = blockIdx.x;                // 4b * 64gt * 2zt = 512
    const int zti = bx & 1;
    const int gt  = (bx >> 1) & 63;
    const int b   = bx >> 7;
    const int g0 = gt * 64, z0 = zti * 64;
    const int tid = threadIdx.x;
    const int zl = tid & 63, gl = tid >> 6;
    #pragma unroll
    for (int i = 0; i < 16; ++i) {
        const int g = gl + i * 4;
        const float v = z[(size_t)(b * G_ + g0 + g) * DZ_ + z0 + zl];
        unsigned int u = __float_as_uint(v);
        u = u + 0x7FFFu + ((u >> 16) & 1u);   // RNE to bf16
        tile[g][zl] = (unsigned short)(u >> 16);
    }
    __syncthreads();
    const int gp = (tid & 31) * 2, zi = tid >> 5;
    const int c  = (g0 + gp) >> 5, gi = gp & 31;
    #pragma unroll
    for (int i = 0; i < 8; ++i) {
        const int zz = zi + i * 8;
        const unsigned int lo = tile[gp][zz], hi = tile[gp + 1][zz];
        *(unsigned int*)(zt + ((size_t)(b * 128 + c) * 128 + z0 + zz) * 32 + gi)
            = lo | (hi << 16);
    }
}

// v8: z-split across BLOCKS (z is an output dim -> no cross-block reduction).
// Grid 512 = 4b x 2zh x 64tt; block = 512 thr (8 waves) = 2ts x 4p.
// Per wave: 16 t x 64 z (4 frags) x 1024 g (32 chunks).  Register budget
// collapses to ~105 (acc[2][4]=32 + bz dbuf 32 + transients) <= 128, so
// __launch_bounds__(512,4) gives 2 INDEPENDENT blocks/CU = 4 waves/SIMD —
// v1's TLP regime with v6's barrier-free conflict-free reg-streaming and no
// added traffic (v7's mistake).  ts-pairs share the B stream (L1 hits, Zt
// L2 traffic stays 256 MB); XCD i serves a fixed (b,zh) 512 KB Zt slice ->
// fully L2-resident.  bz register-double-buffered one chunk ahead; xv
// reloaded per chunk (wait covered by 4-way TLP + 2 indep blocks).
__global__ __launch_bounds__(512, 4)
void setconv_main(const float* __restrict__ xt,
                  const float* __restrict__ xg,
                  const float* __restrict__ lsp,
                  const unsigned short* __restrict__ Zt,
                  float* __restrict__ out)
{
    __shared__ __align__(16) float red[8192];    // 32 KB, reduction only

    const int bx = blockIdx.x;                // 512 blocks = (tt*2+zh)*4 + b
    const int b  = bx & 3;                    // fixed per XCD
    const int zh = (bx >> 2) & 1;             // fixed per XCD
    const int tt = bx >> 3;                   // 0..63
    const int tid  = threadIdx.x;
    const int w    = tid >> 6;
    const int ts   = w >> 2;                  // t-set 0/1
    const int p    = w & 3;                   // g-group 0..3
    const int lane = tid & 63;
    const int quad = lane >> 4;
    const int l15  = lane & 15;
    const int t0   = tt * 32;

    float c00, c01, c10, c11;
    {
        const float h = -0.72134752f;         // -0.5*log2(e)
        float ls;
        ls = 1e-5f + softplus_f(lsp[0]); c00 = h / (ls * ls);
        ls = 1e-5f + softplus_f(lsp[1]); c01 = h / (ls * ls);
        ls = 1e-5f + softplus_f(lsp[2]); c10 = h / (ls * ls);
        ls = 1e-5f + softplus_f(lsp[3]); c11 = h / (ls * ls);
    }

    // this wave's 16 t-rows
    const float xt0 = xt[(size_t)(b * NT_ + t0 + ts * 16 + l15) * 2 + 0];
    const float xt1 = xt[(size_t)(b * NT_ + t0 + ts * 16 + l15) * 2 + 1];

    f32x4 acc[2][4];                          // [k][nt] = 32 regs
    #pragma unroll
    for (int k = 0; k < 2; ++k)
        #pragma unroll
        for (int n = 0; n < 4; ++n) acc[k][n] = (f32x4)0.0f;

    // B-frag base: chunk c at +c*4096 shorts; my z-half's frags at
    // +(zh*4 + ntl)*512; per-lane l15*32 + quad*8 (16 B/lane, coalesced).
    const unsigned short* zb = Zt + (size_t)(b * 128 + p * 32) * 4096
                               + (zh * 4) * 512 + l15 * 32 + quad * 8;
    const float* xgq = xg + (size_t)(b * G_ + p * 1024 + quad * 8) * 2;

    bf16x8 bzA[4], bzB[4];

    // prologue: B(0)
    #pragma unroll
    for (int nt = 0; nt < 4; ++nt)
        bzA[nt] = *(const bf16x8*)(zb + nt * 512);

    #define CHUNK(CH, BZC, BZN)                                                \
    {                                                                          \
        const int ch_ = (CH);                                                  \
        /* xv(ch) first, then bz(ch+1): weights' wait for xv leaves the        \
           newer bz(ch+1) loads in flight; bz(ch) is already retired. */       \
        const float* xp = xgq + ch_ * 64;                                      \
        const float4 xv0 = *(const float4*)(xp + 0);                           \
        const float4 xv1 = *(const float4*)(xp + 4);                           \
        const float4 xv2 = *(const float4*)(xp + 8);                           \
        const float4 xv3 = *(const float4*)(xp + 12);                          \
        if (ch_ < 31) {                                                        \
            const unsigned short* zc = zb + (size_t)(ch_ + 1) * 4096;          \
            _Pragma("unroll")                                                  \
            for (int nt = 0; nt < 4; ++nt)                                     \
                BZN[nt] = *(const bf16x8*)(zc + nt * 512);                     \
        }                                                                      \
        float gx[8], gy[8];                                                    \
        gx[0]=xv0.x; gy[0]=xv0.y; gx[1]=xv0.z; gy[1]=xv0.w;                    \
        gx[2]=xv1.x; gy[2]=xv1.y; gx[3]=xv1.z; gy[3]=xv1.w;                    \
        gx[4]=xv2.x; gy[4]=xv2.y; gx[5]=xv2.z; gy[5]=xv2.w;                    \
        gx[6]=xv3.x; gy[6]=xv3.y; gx[7]=xv3.z; gy[7]=xv3.w;                    \
        union { bf16x8 v; unsigned int u[4]; } a0, a1;                         \
        {                                                                      \
            unsigned int w0b[8], w1b[8];                                       \
            _Pragma("unroll")                                                  \
            for (int j = 0; j < 8; ++j) {                                      \
                const float d0 = xt0 - gx[j];                                  \
                const float d1 = xt1 - gy[j];                                  \
                const float q0 = d0 * d0;                                      \
                const float q1 = d1 * d1;                                      \
                const float e0 = fmaf(q1, c10, q0 * c00);                      \
                const float e1 = fmaf(q1, c11, q0 * c01);                      \
                w0b[j] = __float_as_uint(__builtin_amdgcn_exp2f(e0));          \
                w1b[j] = __float_as_uint(__builtin_amdgcn_exp2f(e1));          \
            }                                                                  \
            _Pragma("unroll")                                                  \
            for (int h = 0; h < 4; ++h) {                                      \
                a0.u[h] = __builtin_amdgcn_perm(w0b[2*h+1], w0b[2*h], 0x07060302u); \
                a1.u[h] = __builtin_amdgcn_perm(w1b[2*h+1], w1b[2*h], 0x07060302u); \
            }                                                                  \
        }                                                                      \
        _Pragma("unroll")                                                      \
        for (int nt = 0; nt < 4; ++nt) {                                       \
            acc[0][nt] = __builtin_amdgcn_mfma_f32_16x16x32_bf16(a0.v, BZC[nt], acc[0][nt], 0, 0, 0); \
            acc[1][nt] = __builtin_amdgcn_mfma_f32_16x16x32_bf16(a1.v, BZC[nt], acc[1][nt], 0, 0, 0); \
        }                                                                      \
    }

    for (int q = 0; q < 16; ++q) {
        CHUNK(2 * q,     bzA, bzB);
        CHUNK(2 * q + 1, bzB, bzA);
    }
    #undef CHUNK

    // ---- 2-round p-reduction per t-set (4 waves each, parallel) ----
    // slot = 2048 f32 (8 KB); 4 slots = 32 KB
    #define RED_W(slot) { \
        float* bp = &red[(slot) * 2048 + lane * 4]; \
        _Pragma("unroll") \
        for (int k = 0; k < 2; ++k) \
            _Pragma("unroll") \
            for (int n = 0; n < 4; ++n) \
                *(f32x4*)(bp + (k * 4 + n) * 256) = acc[k][n]; }
    #define RED_A(slot) { \
        const float* bp = &red[(slot) * 2048 + lane * 4]; \
        _Pragma("unroll") \
        for (int k = 0; k < 2; ++k) \
            _Pragma("unroll") \
            for (int n = 0; n < 4; ++n) \
                acc[k][n] += *(const f32x4*)(bp + (k * 4 + n) * 256); }

    __syncthreads();
    if (p >= 2) RED_W(ts * 2 + (p - 2));      // ts0:{p2->0,p3->1} ts1:{p2->2,p3->3}
    __syncthreads();
    if (p < 2) RED_A(ts * 2 + p);             // p0+=slot(ts*2), p1+=slot(ts*2+1)
    __syncthreads();                          // protect slot overwrite
    if (p == 1) RED_W(ts);                    // ts0p1->slot0, ts1p1->slot1
    __syncthreads();
    if (p == 0) {
        RED_A(ts);
        const int tr = t0 + ts * 16 + quad * 4;
        #pragma unroll
        for (int nt = 0; nt < 4; ++nt) {
            float* ob = out + (size_t)(b * NT_ + tr) * (DZ_ * 2)
                        + (zh * 64 + nt * 16 + l15) * 2;
            #pragma unroll
            for (int r = 0; r < 4; ++r)
                *(float2*)(ob + (size_t)r * (DZ_ * 2)) =
                    make_float2(acc[0][nt][r], acc[1][nt][r]);
        }
    }
    #undef RED_W
    #undef RED_A
}

extern "C" void kernel_launch(void* const* d_in, const int* in_sizes, int n_in,
                              void* d_out, int out_size, void* d_ws, size_t ws_size,
                              hipStream_t stream)
{
    const float* x_grid = (const float*)d_in[0];   // (4,64,64,2)
    const float* z_grid = (const float*)d_in[1];   // (4,64,64,128)
    const float* xt     = (const float*)d_in[2];   // (4,2048,2)
    const float* lsp    = (const float*)d_in[3];   // (2,2)
    float* out = (float*)d_out;                    // (4,2048,256) fp32
    unsigned short* Zt = (unsigned short*)d_ws;    // tiled, 4 MB

    hipLaunchKernelGGL(transpose_z, dim3(512), dim3(256), 0, stream, z_grid, Zt);
    hipLaunchKernelGGL(setconv_main, dim3(512), dim3(512), 0, stream,
                       xt, x_grid, lsp, Zt, out);
}

// Round 10
// 101.702 us; speedup vs baseline: 1.4478x; 1.1626x over previous
//
#include <hip/hip_runtime.h>
#include <hip/hip_bf16.h>
#include <cmath>

#define B_   4
#define NT_  2048
#define G_   4096
#define DZ_  128

typedef __attribute__((ext_vector_type(8))) short bf16x8;
typedef __attribute__((ext_vector_type(8))) short s16x8;
typedef __attribute__((ext_vector_type(4))) float f32x4;

__device__ __forceinline__ float softplus_f(float x) {
    return fmaxf(x, 0.0f) + log1pf(expf(-fabsf(x)));
}

// async 16B global -> LDS (lane i lands at ldst + 16*i; ldst wave-uniform)
__device__ __forceinline__ void gl2lds16(const void* gsrc, void* ldst) {
    __builtin_amdgcn_global_load_lds(
        (const __attribute__((address_space(1))) unsigned int*)gsrc,
        (__attribute__((address_space(3))) unsigned int*)ldst, 16, 0, 0);
}

// v9: z_grid (B,G,DZ) fp32 -> Zt3 FRAG-MAJOR bf16 tiles.
// Chunk c = g>>5 (32 g); frag nt = z>>4 (16 z); within a frag, lane
// (q = (g&31)>>3, l15 = z&15) holds 8 shorts j = g&7 at lane*8:
//   Zt3[ ((b*128 + c)*8 + nt)*512 + (q*16 + l15)*8 + j ]
// => the MFMA B-frag ds_read_b128 is at mytile + nt*512 + lane*8:
//    lane-contiguous 16B -> every 16-lane phase covers all 32 banks 2-deep
//    = CONFLICT-FREE (v1's l15*64B+quad*16B pattern was 8-way, ~1M conflicts).
// Each 8 KB chunk-tile is still contiguous -> the gl2lds DMA is unchanged.
__global__ __launch_bounds__(256, 1)
void transpose_z(const float* __restrict__ z, unsigned short* __restrict__ zt)
{
    __shared__ unsigned short tile[64][66];
    const int bx = blockIdx.x;                // 4b * 64gt * 2zt = 512
    const int zti = bx & 1;
    const int gt  = (bx >> 1) & 63;
    const int b   = bx >> 7;
    const int g0 = gt * 64, z0 = zti * 64;
    const int tid = threadIdx.x;
    const int zl = tid & 63, gl = tid >> 6;
    #pragma unroll
    for (int i = 0; i < 16; ++i) {
        const int g = gl + i * 4;
        const float v = z[(size_t)(b * G_ + g0 + g) * DZ_ + z0 + zl];
        unsigned int u = __float_as_uint(v);
        u = u + 0x7FFFu + ((u >> 16) & 1u);   // RNE to bf16
        tile[g][zl] = (unsigned short)(u >> 16);
    }
    __syncthreads();
    // output: 2 passes x 256 threads, each thread one 16B frag-lane block;
    // consecutive tid -> consecutive 16B => perfectly coalesced 4 KB stores.
    const int nt  = tid >> 6;                 // frag (z-block) 0..3 (local)
    const int q   = (tid >> 4) & 3;           // g-octet within chunk
    const int fl  = tid & 15;                 // l15 (z within frag)
    #pragma unroll
    for (int i = 0; i < 2; ++i) {             // chunk-local (c = gt*2 + i)
        s16x8 v;
        #pragma unroll
        for (int j = 0; j < 8; ++j)
            v[j] = (short)tile[i * 32 + q * 8 + j][nt * 16 + fl];
        *(s16x8*)(zt + ((size_t)(b * 128 + gt * 2 + i) * 8 + zti * 4 + nt) * 512
                  + (size_t)(q * 16 + fl) * 8) = v;
    }
}

// v9 main: byte-identical to the proven v1 structure (fastest measured, ~38 µs):
// 512 blocks x 8 waves (16 waves/CU = 4/SIMD), Tt=16, 8-way kh g-split,
// private single-buffered 8 KB LDS slot per wave, gl2lds DMA, vmcnt(0) drain,
// xv register-prefetched one chunk ahead, 3-round k-reduction.
// ONLY change: B-frag ds_read addr = mytile + nt*512 + lane*8 (conflict-free
// under the new frag-major Zt layout; same data per lane as before).
__global__ __launch_bounds__(512, 4)
void setconv_main(const float* __restrict__ xt,
                  const float* __restrict__ xg,
                  const float* __restrict__ lsp,
                  const unsigned short* __restrict__ Zt,
                  float* __restrict__ out)
{
    __shared__ __align__(16) unsigned short lds[32768];  // 64 KB: 8 wave-tiles / red

    // XCD swizzle: bx = tt2*8 + b*2 + p -> same-b blocks on 2 XCDs
    const int bx = blockIdx.x;
    const int b  = (bx >> 1) & 3;
    const int tt = ((bx >> 3) << 1) | (bx & 1);   // 0..127
    const int tid  = threadIdx.x;
    const int w    = tid >> 6;                // = kh, 0..7
    const int lane = tid & 63;
    const int quad = lane >> 4;
    const int l15  = lane & 15;
    const int t0   = tt * 16;

    float c00, c01, c10, c11;
    {
        const float h = -0.72134752f;         // -0.5*log2(e)
        float ls;
        ls = 1e-5f + softplus_f(lsp[0]); c00 = h / (ls * ls);
        ls = 1e-5f + softplus_f(lsp[1]); c01 = h / (ls * ls);
        ls = 1e-5f + softplus_f(lsp[2]); c10 = h / (ls * ls);
        ls = 1e-5f + softplus_f(lsp[3]); c11 = h / (ls * ls);
    }

    // A-frag row m = l15 -> per-lane t constants
    const float xt0 = xt[(size_t)(b * NT_ + t0 + l15) * 2 + 0];
    const float xt1 = xt[(size_t)(b * NT_ + t0 + l15) * 2 + 1];

    f32x4 acc[2][8];
    #pragma unroll
    for (int k = 0; k < 2; ++k)
        #pragma unroll
        for (int n = 0; n < 8; ++n) acc[k][n] = (f32x4)0.0f;

    unsigned short* const mytile = lds + w * 4096;       // private 8 KB slot
    const float* xgq = xg + (size_t)(b * G_ + w * 512 + quad * 8) * 2;

    // prologue: xv(0) first (so weights(0) wait leaves stage(0) in flight)
    float4 xv0 = *(const float4*)(xgq + 0);
    float4 xv1 = *(const float4*)(xgq + 4);
    float4 xv2 = *(const float4*)(xgq + 8);
    float4 xv3 = *(const float4*)(xgq + 12);
    {
        const unsigned short* zs = Zt + (size_t)(b * 128 + w * 16) * 4096 + lane * 8;
        #pragma unroll
        for (int i = 0; i < 8; ++i)
            gl2lds16(zs + i * 512, mytile + i * 512);
    }

    #pragma unroll
    for (int ch = 0; ch < 16; ++ch) {
        // ---- weights(ch) from xv (loaded >=1 chunk ago; no fresh vm wait) ----
        float gx[8], gy[8];
        gx[0]=xv0.x; gy[0]=xv0.y; gx[1]=xv0.z; gy[1]=xv0.w;
        gx[2]=xv1.x; gy[2]=xv1.y; gx[3]=xv1.z; gy[3]=xv1.w;
        gx[4]=xv2.x; gy[4]=xv2.y; gx[5]=xv2.z; gy[5]=xv2.w;
        gx[6]=xv3.x; gy[6]=xv3.y; gx[7]=xv3.z; gy[7]=xv3.w;
        unsigned int w0b[8], w1b[8];
        #pragma unroll
        for (int j = 0; j < 8; ++j) {
            const float d0 = xt0 - gx[j];
            const float d1 = xt1 - gy[j];
            const float q0 = d0 * d0;
            const float q1 = d1 * d1;
            const float e0 = fmaf(q1, c10, q0 * c00);
            const float e1 = fmaf(q1, c11, q0 * c01);
            w0b[j] = __float_as_uint(__builtin_amdgcn_exp2f(e0));
            w1b[j] = __float_as_uint(__builtin_amdgcn_exp2f(e1));
        }
        union { bf16x8 v; unsigned int u[4]; } a0, a1;
        #pragma unroll
        for (int h = 0; h < 4; ++h) {
            a0.u[h] = __builtin_amdgcn_perm(w0b[2*h+1], w0b[2*h], 0x07060302u);
            a1.u[h] = __builtin_amdgcn_perm(w1b[2*h+1], w1b[2*h], 0x07060302u);
        }

        // ---- drain this chunk's DMA (issued a full phase ago), then xv(ch+1) ----
        __builtin_amdgcn_s_waitcnt(0x0F70);          // vmcnt(0)
        if (ch < 15) {
            const float* xp = xgq + (ch + 1) * 64;
            xv0 = *(const float4*)(xp + 0);
            xv1 = *(const float4*)(xp + 4);
            xv2 = *(const float4*)(xp + 8);
            xv3 = *(const float4*)(xp + 12);
        }

        // ---- consume LDS tile: conflict-free lane-contiguous ds_read_b128 ----
        #pragma unroll
        for (int nt = 0; nt < 8; ++nt) {
            const bf16x8 bz = *(const bf16x8*)(mytile + nt * 512 + lane * 8);
            acc[0][nt] = __builtin_amdgcn_mfma_f32_16x16x32_bf16(a0.v, bz, acc[0][nt], 0, 0, 0);
            acc[1][nt] = __builtin_amdgcn_mfma_f32_16x16x32_bf16(a1.v, bz, acc[1][nt], 0, 0, 0);
        }

        // ---- stage(ch+1) into the (now fully-read) private tile ----
        if (ch < 15) {
            const unsigned short* zs = Zt + (size_t)(b * 128 + w * 16 + ch + 1) * 4096
                                       + lane * 8;
            #pragma unroll
            for (int i = 0; i < 8; ++i)
                gl2lds16(zs + i * 512, mytile + i * 512);
        }
    }

    // ---- 3-round k-reduction over the 8 kh-waves (aliases wave tiles) ----
    float* const red = (float*)lds;
    #define RED_W(slot) { \
        float* bp = &red[(slot) * 4096 + lane * 4]; \
        _Pragma("unroll") \
        for (int k = 0; k < 2; ++k) \
            _Pragma("unroll") \
            for (int n = 0; n < 8; ++n) \
                *(f32x4*)(bp + (k * 8 + n) * 256) = acc[k][n]; }
    #define RED_A(slot) { \
        const float* bp = &red[(slot) * 4096 + lane * 4]; \
        _Pragma("unroll") \
        for (int k = 0; k < 2; ++k) \
            _Pragma("unroll") \
            for (int n = 0; n < 8; ++n) \
                acc[k][n] += *(const f32x4*)(bp + (k * 8 + n) * 256); }

    __syncthreads();
    if (w >= 4) RED_W(w - 4);
    __syncthreads();
    if (w < 4) RED_A(w);
    if (w == 2 || w == 3) RED_W(w);
    __syncthreads();
    if (w < 2) RED_A(w + 2);
    if (w == 1) RED_W(3);
    __syncthreads();
    if (w == 0) {
        RED_A(3);
        const int tr = t0 + quad * 4;
        #pragma unroll
        for (int nt = 0; nt < 8; ++nt) {
            float* ob = out + (size_t)(b * NT_ + tr) * (DZ_ * 2) + (nt * 16 + l15) * 2;
            #pragma unroll
            for (int r = 0; r < 4; ++r)
                *(float2*)(ob + (size_t)r * (DZ_ * 2)) =
                    make_float2(acc[0][nt][r], acc[1][nt][r]);
        }
    }
    #undef RED_W
    #undef RED_A
}

extern "C" void kernel_launch(void* const* d_in, const int* in_sizes, int n_in,
                              void* d_out, int out_size, void* d_ws, size_t ws_size,
                              hipStream_t stream)
{
    const float* x_grid = (const float*)d_in[0];   // (4,64,64,2)
    const float* z_grid = (const float*)d_in[1];   // (4,64,64,128)
    const float* xt     = (const float*)d_in[2];   // (4,2048,2)
    const float* lsp    = (const float*)d_in[3];   // (2,2)
    float* out = (float*)d_out;                    // (4,2048,256) fp32
    unsigned short* Zt = (unsigned short*)d_ws;    // tiled, 4 MB

    hipLaunchKernelGGL(transpose_z, dim3(512), dim3(256), 0, stream, z_grid, Zt);
    hipLaunchKernelGGL(setconv_main, dim3(512), dim3(512), 0, stream,
                       xt, x_grid, lsp, Zt, out);
}